// Round 18
// baseline (331.264 us; speedup 1.0000x reference)
//
#include <hip/hip_runtime.h>
#include <math.h>
#include <stdint.h>

#define HIDDEN 4096
#define NEXP   64
#define TOKS   64                 // tokens per gemm block
#define KBLK   2048               // K per block (split-K x2)
#define KCH    64                 // k floats per staged chunk
#define NCHK   (KBLK / KCH)       // 32 chunks
#define X_FL   (TOKS * KCH)       // 4096 floats: X region (16 KB)
#define PAR_FL (X_FL + 2 * 2048)  // + Bhi 8KB + Blo 8KB = 8192 floats (32 KB)

typedef __bf16 bf16x8 __attribute__((ext_vector_type(8)));
typedef float  f32x4  __attribute__((ext_vector_type(4)));

union BfU { uint4 u; bf16x8 b; };

// fp32 -> (hi, lo) bf16 split; dropped lo*lo term ~2^-18 rel (R8-R17 verified).
static __device__ __forceinline__ void cvt_hilo(const float* x8, bf16x8& hi, bf16x8& lo) {
#pragma unroll
    for (int j = 0; j < 8; ++j) {
        const float x = x8[j];
        const __bf16 h = (__bf16)x;
        const float  r = x - (float)h;
        hi[j] = h;
        lo[j] = (__bf16)r;
    }
}

// async global->LDS, 16B/lane, wave-uniform dest base + lane*16
__device__ __forceinline__ void gload_lds16(const void* g, void* l) {
    __builtin_amdgcn_global_load_lds(
        (const __attribute__((address_space(1))) void*)g,
        (__attribute__((address_space(3))) void*)l, 16, 0, 0);
}

// ---- pre-kernel (R8-R17 verified): W fp32 -> B-fragment-ordered bf16 hi/lo.
// Also zeroes the per-tile split-K counters (re-runs every graph replay, so
// counters are reset before each gemm launch -- replay-safe).
__global__ __launch_bounds__(128) void wconv_kernel(
    const float* __restrict__ W, ushort* __restrict__ wsHi, ushort* __restrict__ wsLo,
    int* __restrict__ cnt)
{
    const int gid = blockIdx.x * blockDim.x + threadIdx.x;   // 0..32767
    if (gid < 256) cnt[gid] = 0;
    const int S = gid >> 8;
    const int e = (gid >> 6) & 3;
    const int l = gid & 63;
    const int row = 16 * e + (l & 15);
    const int k0  = 32 * S + 8 * (l >> 4);
    const float* src = W + (size_t)row * HIDDEN + k0;
    float x8[8];
    *(float4*)&x8[0] = *(const float4*)src;
    *(float4*)&x8[4] = *(const float4*)(src + 4);
    BfU hi, lo;
    cvt_hilo(x8, hi.b, lo.b);
    const size_t o = ((size_t)(S * 4 + e) * 64 + l) * 8;
    *(uint4*)(wsHi + o) = hi.u;
    *(uint4*)(wsLo + o) = lo.u;
}

// ---- gemm half + fused last-block combine. Main loop = R17 VERBATIM (67us
// total, best). Epilogue: write raw partial (h0 -> logits region, h1 -> ws),
// device-scope release fence, atomicAdd per-tile counter; the SECOND
// finisher acquire-fences, reads the partner partial (own still in regs),
// adds bias, writes final logits + top-2/softmax. Sum of exactly 2 partials
// in fixed order => bitwise deterministic whichever block wins. Deletes the
// combine dispatch + gap (~4us) and its 4MB logits re-read.
__global__ __launch_bounds__(512, 2) void gemm_half_kernel(
    const float* __restrict__ X,
    const ushort* __restrict__ wsHi, const ushort* __restrict__ wsLo,
    const float* __restrict__ Bv,
    float* __restrict__ out, float* __restrict__ wsP,
    int* __restrict__ cnt, int nTok)
{
    __shared__ float smem[2 * PAR_FL];   // 65536 B; epilogue aliases
    __shared__ int   flag;

    const int tid = threadIdx.x;
    const int wv  = tid >> 6;        // 0..7
    const int tg  = wv >> 1;         // token-group 0..3
    const int kh  = wv & 1;          // k-step within chunk 0..1
    const int l   = tid & 63;
    const int g   = l >> 4;          // k-slot group 0..3
    const int cr  = l & 15;          // A row / B col within tile
    const int bx  = blockIdx.x;
    const int h   = bx & 1;          // K-half
    const int t0  = (bx >> 1) * TOKS;

    const size_t offLog = (size_t)nTok * 4;
    float* outLog = out + offLog;

    // X staging (R13/R17-verified KCH=64 forms)
    const float* XgS[2];
    int xdst[2];
#pragma unroll
    for (int r = 0; r < 2; ++r) {
        const int q    = 2 * wv + r;
        const int srow = 4 * q + (l >> 4);
        const int sgr  = (l & 8) | ((l & 7) ^ (srow & 7));
        XgS[r]  = X + (size_t)(t0 + srow) * HIDDEN + h * KBLK + sgr * 4;
        xdst[r] = 4 * q * KCH;       // floats (uniform base)
    }
    // B staging (R17-verified): wave wv stages hi/lo frag slot wv (1KB linear)
    const ushort* BhS = wsHi + (size_t)h * 131072 + (size_t)wv * 512 + (size_t)l * 8;
    const ushort* BlS = wsLo + (size_t)h * 131072 + (size_t)wv * 512 + (size_t)l * 8;
    const int bhdst = X_FL + wv * 256;
    const int bldst = X_FL + 2048 + wv * 256;

    // A-frag read (R17-verified)
    const int m8   = cr & 7;
    const int rowX = (16 * tg + cr) * KCH;
    const int gA0  = (8 * kh + ((2 * g + 0) ^ m8)) << 2;
    const int gA1  = (8 * kh + ((2 * g + 1) ^ m8)) << 2;

    f32x4 acc[4] = {{0.f,0.f,0.f,0.f},{0.f,0.f,0.f,0.f},{0.f,0.f,0.f,0.f},{0.f,0.f,0.f,0.f}};

    // prologue: stage chunk 0 -> parity 0, chunk 1 -> parity 1
#pragma unroll
    for (int r = 0; r < 2; ++r) gload_lds16(XgS[r], smem + xdst[r]);
    gload_lds16(BhS, smem + bhdst);
    gload_lds16(BlS, smem + bldst);
#pragma unroll
    for (int r = 0; r < 2; ++r) gload_lds16(XgS[r] + KCH, smem + PAR_FL + xdst[r]);
    gload_lds16(BhS + 4096, smem + PAR_FL + bhdst);
    gload_lds16(BlS + 4096, smem + PAR_FL + bldst);

#pragma unroll 1
    for (int c = 0; c < NCHK; ++c) {
        if (c + 1 < NCHK) asm volatile("s_waitcnt vmcnt(4)" ::: "memory");
        else              asm volatile("s_waitcnt vmcnt(0)" ::: "memory");
        __builtin_amdgcn_s_barrier();          // B1: chunk c staged & visible
        const int p = c & 1;
        {
            const float*  xb = smem + p * PAR_FL;
            const ushort* bh = (const ushort*)(xb + X_FL) + (4 * kh) * 512 + l * 8;
            const ushort* bl = bh + 4096;      // Blo region (+2048 floats)
            float x8[8];
            *(float4*)&x8[0] = *(const float4*)(xb + rowX + gA0);
            *(float4*)&x8[4] = *(const float4*)(xb + rowX + gA1);
            bf16x8 xh, xo; cvt_hilo(x8, xh, xo);
#pragma unroll
            for (int e = 0; e < 4; ++e) {
                BfU ph, pl;
                ph.u = *(const uint4*)(bh + e * 512);
                pl.u = *(const uint4*)(bl + e * 512);
                acc[e] = __builtin_amdgcn_mfma_f32_16x16x32_bf16(xh, ph.b, acc[e], 0, 0, 0);
                acc[e] = __builtin_amdgcn_mfma_f32_16x16x32_bf16(xo, ph.b, acc[e], 0, 0, 0);
                acc[e] = __builtin_amdgcn_mfma_f32_16x16x32_bf16(xh, pl.b, acc[e], 0, 0, 0);
            }
        }
        __builtin_amdgcn_s_barrier();          // B2: all reads of parity p done
        if (c + 2 < NCHK) {                    // issue c+2 -> parity p (freed)
            float* pb = smem + p * PAR_FL;
            const int ko = (c + 2) * KCH;
            const size_t bo = (size_t)(c + 2) * 4096;
#pragma unroll
            for (int r = 0; r < 2; ++r) gload_lds16(XgS[r] + ko, pb + xdst[r]);
            gload_lds16(BhS + bo, pb + bhdst);
            gload_lds16(BlS + bo, pb + bldst);
        }
    }

    __syncthreads();   // full drain; safe to alias LDS

    // ---- combine kh partials in LDS (R17-verified)
    float (*tiles)[64][68] = (float (*)[64][68])smem;   // 2*64*68 floats
#pragma unroll
    for (int e = 0; e < 4; ++e)
#pragma unroll
        for (int i = 0; i < 4; ++i)
            tiles[kh][16 * tg + 4 * g + i][16 * e + cr] = acc[e][i];   // C/D (m89)
    __syncthreads();

    // my partial rows (regs): tok = tid>>3, experts e8..e8+7
    const int tok = tid >> 3;
    const int e8  = (tid & 7) * 8;
    float v[8];
#pragma unroll
    for (int j = 0; j < 8; ++j)
        v[j] = tiles[0][tok][e8 + j] + tiles[1][tok][e8 + j];

    // write raw partial: h0 -> logits region, h1 -> ws
    {
        float* rowp = (h ? wsP : outLog) + (size_t)(t0 + tok) * NEXP + e8;
        *(float4*)rowp       = make_float4(v[0], v[1], v[2], v[3]);
        *(float4*)(rowp + 4) = make_float4(v[4], v[5], v[6], v[7]);
    }
    __threadfence();                           // release (device scope, cross-XCD)
    if (tid == 0) flag = atomicAdd(&cnt[bx >> 1], 1);
    __syncthreads();

    if (flag == 1) {                           // I'm the second finisher: combine
        __threadfence();                       // acquire
        const float* pp = (h ? outLog : wsP) + (size_t)(t0 + tok) * NEXP + e8;
        const float4 pa = *(const float4*)pp;
        const float4 pb = *(const float4*)(pp + 4);
        const float4 b0 = *(const float4*)(Bv + e8);
        const float4 b1 = *(const float4*)(Bv + e8 + 4);
        float f[8] = { v[0] + pa.x + b0.x, v[1] + pa.y + b0.y,
                       v[2] + pa.z + b0.z, v[3] + pa.w + b0.w,
                       v[4] + pb.x + b1.x, v[5] + pb.y + b1.y,
                       v[6] + pb.z + b1.z, v[7] + pb.w + b1.w };
        float* rowp = outLog + (size_t)(t0 + tok) * NEXP + e8;
        *(float4*)rowp       = make_float4(f[0], f[1], f[2], f[3]);
        *(float4*)(rowp + 4) = make_float4(f[4], f[5], f[6], f[7]);

        // transposed tile for top-2 (tiles region dead; all reads done pre-atomic)
        float* tt = smem;                      // 64*65 floats
#pragma unroll
        for (int j = 0; j < 8; ++j)
            tt[(e8 + j) * 65 + tok] = f[j];
        __syncthreads();

        // top-2 + softmax (verified): strict > keeps lowest index on ties
        if (tid < 64) {
            const int t = tid;
            float m1 = -INFINITY, m2 = -INFINITY;
            int i1 = 0, i2 = 0;
#pragma unroll
            for (int e = 0; e < NEXP; ++e) {
                const float vv = tt[e * 65 + t];
                if (vv > m1)      { m2 = m1; i2 = i1; m1 = vv; i1 = e; }
                else if (vv > m2) { m2 = vv; i2 = e; }
            }
            const float ex  = expf(m2 - m1);
            const float inv = 1.0f / (1.0f + ex);
            *(float2*)(out + (size_t)(t0 + t) * 2) = make_float2(inv, ex * inv);
            *(float2*)(out + (size_t)nTok * 2 + (size_t)(t0 + t) * 2) =
                make_float2((float)i1, (float)i2);
        }
        if ((bx >> 1) == 0 && tid == 0)
            out[offLog + (size_t)nTok * NEXP] = 0.0f;   // aux_loss (0 either way)
    }
}

extern "C" void kernel_launch(void* const* d_in, const int* in_sizes, int n_in,
                              void* d_out, int out_size, void* d_ws, size_t ws_size,
                              hipStream_t stream)
{
    const float* X  = (const float*)d_in[0];
    const float* W  = (const float*)d_in[1];
    const float* Bv = (const float*)d_in[2];
    float* out = (float*)d_out;
    const int nTok  = in_sizes[0] / HIDDEN;   // 16384
    const int tiles = nTok / TOKS;            // 256
    ushort* wsHi = (ushort*)d_ws;                         // 512 KB
    ushort* wsLo = wsHi + (size_t)NEXP * HIDDEN;          // 512 KB
    int*    cnt  = (int*)(wsLo + (size_t)NEXP * HIDDEN);  // 1 KB counters
    float*  wsP  = (float*)(cnt + 256);                   // 4 MB h1 partials

    wconv_kernel<<<256, 128, 0, stream>>>(W, wsHi, wsLo, cnt);
    gemm_half_kernel<<<2 * tiles, 512, 0, stream>>>(X, wsHi, wsLo, Bv, out, wsP, cnt, nTok);
}

// Round 19
// 70.931 us; speedup vs baseline: 4.6702x; 4.6702x over previous
//
#include <hip/hip_runtime.h>
#include <math.h>
#include <stdint.h>

#define HIDDEN 4096
#define NEXP   64
#define TOKS   64                 // tokens per gemm block
#define NSPLIT 4                  // split-K factor
#define KBLK   (HIDDEN / NSPLIT)  // 1024 K per block
#define KCH    32                 // k floats per staged chunk (1 MFMA k-step)
#define NCHK   (KBLK / KCH)       // 32 chunks
#define X_FL   (TOKS * KCH)       // 2048 floats: X region (8 KB)
#define PAR_FL (X_FL + 2 * 1024)  // + Bhi 4KB + Blo 4KB = 4096 floats (16 KB)

typedef __bf16 bf16x8 __attribute__((ext_vector_type(8)));
typedef float  f32x4  __attribute__((ext_vector_type(4)));

union BfU { uint4 u; bf16x8 b; };

// fp32 -> (hi, lo) bf16 split; dropped lo*lo term ~2^-18 rel (R8-R18 verified).
static __device__ __forceinline__ void cvt_hilo(const float* x8, bf16x8& hi, bf16x8& lo) {
#pragma unroll
    for (int j = 0; j < 8; ++j) {
        const float x = x8[j];
        const __bf16 h = (__bf16)x;
        const float  r = x - (float)h;
        hi[j] = h;
        lo[j] = (__bf16)r;
    }
}

// async global->LDS, 16B/lane, wave-uniform dest base + lane*16
__device__ __forceinline__ void gload_lds16(const void* g, void* l) {
    __builtin_amdgcn_global_load_lds(
        (const __attribute__((address_space(1))) void*)g,
        (__attribute__((address_space(3))) void*)l, 16, 0, 0);
}

// ---- pre-kernel (R8-R18 verified): W fp32 -> B-fragment-ordered bf16 hi/lo.
// Fragment F = S*4 + e (S = k-step of 32): lane l supplies
// B[col 16e+(l&15)][k 32S+8(l>>4)+j] at ws[F*512 + l*8].
__global__ __launch_bounds__(128) void wconv_kernel(
    const float* __restrict__ W, ushort* __restrict__ wsHi, ushort* __restrict__ wsLo)
{
    const int gid = blockIdx.x * blockDim.x + threadIdx.x;   // 0..32767
    const int S = gid >> 8;
    const int e = (gid >> 6) & 3;
    const int l = gid & 63;
    const int row = 16 * e + (l & 15);
    const int k0  = 32 * S + 8 * (l >> 4);
    const float* src = W + (size_t)row * HIDDEN + k0;
    float x8[8];
    *(float4*)&x8[0] = *(const float4*)src;
    *(float4*)&x8[4] = *(const float4*)(src + 4);
    BfU hi, lo;
    cvt_hilo(x8, hi.b, lo.b);
    const size_t o = ((size_t)(S * 4 + e) * 64 + l) * 8;
    *(uint4*)(wsHi + o) = hi.u;
    *(uint4*)(wsLo + o) = lo.u;
}

// ---- gemm quarter: R17's counted-vmcnt 2-barrier pipeline scaled to FOUR
// blocks/CU (1024 blocks = 256 tiles x 4 K-quarters; LDS 32KB, VGPR<=64 --
// R18 measured 52 for this loop). R17 proved 2-block overlap covers B1
// stalls (+3.6us); 4-way coverage ~87%. Total B staging is split-K
// INVARIANT (tiles x 1MB) so R12's over-staging poison doesn't apply.
// 8 waves = tg(4) x eh(2); acc[2]; chunk = one full MFMA k-step (K=32).
// vmcnt(2) + raw s_barrier keeps chunk c+1's 2 loads in flight. NO
// cross-block fences (R18's cross-XCD coherence disaster): combine kernel.
__global__ __launch_bounds__(512, 4) void gemm_q_kernel(
    const float* __restrict__ X,
    const ushort* __restrict__ wsHi, const ushort* __restrict__ wsLo,
    float* __restrict__ outLog, float* __restrict__ wsP, int nTok)
{
    __shared__ float smem[2 * PAR_FL];   // 32768 B; epilogue aliases

    const int tid = threadIdx.x;
    const int wv  = tid >> 6;        // 0..7
    const int tg  = wv >> 1;         // token-group 0..3
    const int eh  = wv & 1;          // expert-half 0..1 (32 experts each)
    const int l   = tid & 63;
    const int g   = l >> 4;          // k-slot group 0..3
    const int cr  = l & 15;          // A row / B col within tile
    const int bx  = blockIdx.x;
    const int h   = bx & 3;          // K-quarter
    const int t0  = (bx >> 2) * TOKS;

    // X staging: instr wv covers rows 8wv..8wv+7 (128B each); lane l ->
    // row 8wv+(l>>3), dest granule l&7; source granule (l&7)^(l>>3)
    // (row&7 == l>>3; involution -- verified family).
    const int srow = 8 * wv + (l >> 3);
    const int sgr  = (l & 7) ^ (l >> 3);
    const float* XgS = X + (size_t)(t0 + srow) * HIDDEN + h * KBLK + sgr * 4;
    const int xdst  = wv * 256;      // floats (uniform base; 8 rows x 32 fl)

    // B staging: chunk c window = frags [(32h+c)*4, +4) per plane (2KB);
    // wave wv<4 stages hi frag slot wv, wv>=4 lo frag slot wv-4 (0.5KB... 1 instr).
    const ushort* BS = (wv < 4 ? wsHi : wsLo)
                     + (size_t)h * 65536 + (size_t)(wv & 3) * 512 + (size_t)l * 8;
    const int bdst = X_FL + (wv < 4 ? 0 : 1024) + (wv & 3) * 256;

    // A-frag read: row 16tg+cr, granules (2g+h')^(cr&7)  [verified family]
    const int m8   = cr & 7;
    const int rowX = (16 * tg + cr) * KCH;
    const int gA0  = ((2 * g + 0) ^ m8) << 2;
    const int gA1  = ((2 * g + 1) ^ m8) << 2;

    f32x4 acc[2] = {{0.f,0.f,0.f,0.f},{0.f,0.f,0.f,0.f}};

    // prologue: stage chunk 0 -> parity 0, chunk 1 -> parity 1
    gload_lds16(XgS, smem + xdst);
    gload_lds16(BS, smem + bdst);
    gload_lds16(XgS + KCH, smem + PAR_FL + xdst);
    gload_lds16(BS + 2048, smem + PAR_FL + bdst);

#pragma unroll 1
    for (int c = 0; c < NCHK; ++c) {
        if (c + 1 < NCHK) asm volatile("s_waitcnt vmcnt(2)" ::: "memory");
        else              asm volatile("s_waitcnt vmcnt(0)" ::: "memory");
        __builtin_amdgcn_s_barrier();          // B1: chunk c staged & visible
        const int p = c & 1;
        {
            const float*  xb = smem + p * PAR_FL;
            const ushort* bh = (const ushort*)(xb + X_FL) + (2 * eh) * 512 + l * 8;
            const ushort* bl = bh + 2048;      // Blo region (+1024 floats)
            float x8[8];
            *(float4*)&x8[0] = *(const float4*)(xb + rowX + gA0);
            *(float4*)&x8[4] = *(const float4*)(xb + rowX + gA1);
            bf16x8 xh, xo; cvt_hilo(x8, xh, xo);
#pragma unroll
            for (int e = 0; e < 2; ++e) {
                BfU ph, pl;
                ph.u = *(const uint4*)(bh + e * 512);
                pl.u = *(const uint4*)(bl + e * 512);
                acc[e] = __builtin_amdgcn_mfma_f32_16x16x32_bf16(xh, ph.b, acc[e], 0, 0, 0);
                acc[e] = __builtin_amdgcn_mfma_f32_16x16x32_bf16(xo, ph.b, acc[e], 0, 0, 0);
                acc[e] = __builtin_amdgcn_mfma_f32_16x16x32_bf16(xh, pl.b, acc[e], 0, 0, 0);
            }
        }
        __builtin_amdgcn_s_barrier();          // B2: all reads of parity p done
        if (c + 2 < NCHK) {                    // issue c+2 -> parity p (freed)
            float* pb = smem + p * PAR_FL;
            gload_lds16(XgS + (c + 2) * KCH, pb + xdst);
            gload_lds16(BS + (size_t)(c + 2) * 2048, pb + bdst);
        }
    }

    __syncthreads();   // full drain; safe to alias LDS

    // ---- write raw 64x64 partial via LDS transpose tile (C/D layout m89):
    // row = 16tg + 4g + i, col = 16*(2eh+e) + cr. Full K in acc (no kh combine).
    float (*tiles)[68] = (float (*)[68])smem;   // 64*68 floats (17KB)
#pragma unroll
    for (int e = 0; e < 2; ++e) {
        const int e2 = 2 * eh + e;
#pragma unroll
        for (int i = 0; i < 4; ++i)
            tiles[16 * tg + 4 * g + i][16 * e2 + cr] = acc[e][i];
    }
    __syncthreads();

    {
        float* dst = (h ? wsP + (size_t)(h - 1) * nTok * NEXP : outLog) + (size_t)t0 * NEXP;
        const int tok = tid >> 3;          // 0..63
        const int e8  = (tid & 7) * 8;
        float* rowp = dst + (size_t)tok * NEXP + e8;
        *(float4*)rowp       = *(const float4*)&tiles[tok][e8];
        *(float4*)(rowp + 4) = *(const float4*)&tiles[tok][e8 + 4];
    }
}

// Combine (R17-verified pattern, 4 partials): logits = p0 (logits region)
// + p1+p2+p3 (ws) + bias; top-2 + softmax, strict > keeps lowest index.
__global__ __launch_bounds__(256) void combine_kernel(
    const float* __restrict__ wsP,
    const float* __restrict__ Bv,
    float* __restrict__ out, int nTok)
{
    __shared__ float tt[64 * 65];
    const int tid = threadIdx.x;
    const int t0  = blockIdx.x * TOKS;
    const size_t offSel = (size_t)nTok * 2;
    const size_t offLog = (size_t)nTok * 4;
    const size_t psz    = (size_t)nTok * NEXP;
    float*       L  = out + offLog + (size_t)t0 * NEXP;
    const float* P1 = wsP + (size_t)t0 * NEXP;

#pragma unroll
    for (int r = 0; r < 4; ++r) {
        const int idx = r * 256 + tid;        // 0..1023 float4-chunks
        const int tok = idx >> 4;
        const int e4  = (idx & 15) * 4;
        const float4 a  = *(const float4*)(L + tok * NEXP + e4);
        const float4 b  = *(const float4*)(P1 + tok * NEXP + e4);
        const float4 c  = *(const float4*)(P1 + psz + tok * NEXP + e4);
        const float4 d  = *(const float4*)(P1 + 2 * psz + tok * NEXP + e4);
        const float4 bb = *(const float4*)(Bv + e4);
        const float4 s = make_float4(a.x + b.x + c.x + d.x + bb.x,
                                     a.y + b.y + c.y + d.y + bb.y,
                                     a.z + b.z + c.z + d.z + bb.z,
                                     a.w + b.w + c.w + d.w + bb.w);
        *(float4*)(L + tok * NEXP + e4) = s;
        tt[(e4 + 0) * 65 + tok] = s.x;
        tt[(e4 + 1) * 65 + tok] = s.y;
        tt[(e4 + 2) * 65 + tok] = s.z;
        tt[(e4 + 3) * 65 + tok] = s.w;
    }
    __syncthreads();

    if (tid < 64) {
        const int t = tid;
        float m1 = -INFINITY, m2 = -INFINITY;
        int i1 = 0, i2 = 0;
#pragma unroll
        for (int e = 0; e < NEXP; ++e) {
            const float v = tt[e * 65 + t];
            if (v > m1)      { m2 = m1; i2 = i1; m1 = v; i1 = e; }
            else if (v > m2) { m2 = v; i2 = e; }
        }
        const float ex  = expf(m2 - m1);
        const float inv = 1.0f / (1.0f + ex);
        *(float2*)(out + (size_t)(t0 + tid) * 2)          = make_float2(inv, ex * inv);
        *(float2*)(out + offSel + (size_t)(t0 + tid) * 2) = make_float2((float)i1, (float)i2);
    }

    if (blockIdx.x == 0 && tid == 0)
        out[offLog + (size_t)nTok * NEXP] = 0.0f;   // aux_loss
}

extern "C" void kernel_launch(void* const* d_in, const int* in_sizes, int n_in,
                              void* d_out, int out_size, void* d_ws, size_t ws_size,
                              hipStream_t stream)
{
    const float* X  = (const float*)d_in[0];
    const float* W  = (const float*)d_in[1];
    const float* Bv = (const float*)d_in[2];
    float* out = (float*)d_out;
    const int nTok  = in_sizes[0] / HIDDEN;   // 16384
    const int tiles = nTok / TOKS;            // 256
    ushort* wsHi = (ushort*)d_ws;                        // 512 KB
    ushort* wsLo = wsHi + (size_t)NEXP * HIDDEN;         // 512 KB
    float*  wsP  = (float*)(wsLo + (size_t)NEXP * HIDDEN);  // 12 MB partials
    float*  outLog = out + (size_t)nTok * 4;

    wconv_kernel<<<256, 128, 0, stream>>>(W, wsHi, wsLo);
    gemm_q_kernel<<<NSPLIT * tiles, 512, 0, stream>>>(X, wsHi, wsLo, outLog, wsP, nTok);
    combine_kernel<<<tiles, 256, 0, stream>>>(wsP, Bv, out, nTok);
}

// Round 20
// 67.013 us; speedup vs baseline: 4.9432x; 1.0585x over previous
//
#include <hip/hip_runtime.h>
#include <math.h>
#include <stdint.h>

#define HIDDEN 4096
#define NEXP   64
#define TOKS   64                 // tokens per gemm block
#define KBLK   2048               // K per block (split-K x2)
#define KCH    64                 // k floats per staged chunk
#define NCHK   (KBLK / KCH)       // 32 chunks
#define X_FL   (TOKS * KCH)       // 4096 floats: X region (16 KB)
#define PAR_FL (X_FL + 2 * 2048)  // + Bhi 8KB + Blo 8KB = 8192 floats (32 KB)

typedef __bf16 bf16x8 __attribute__((ext_vector_type(8)));
typedef float  f32x4  __attribute__((ext_vector_type(4)));

union BfU { uint4 u; bf16x8 b; };

// fp32 -> (hi, lo) bf16 split; dropped lo*lo term ~2^-18 rel (R8-R17 verified).
static __device__ __forceinline__ void cvt_hilo(const float* x8, bf16x8& hi, bf16x8& lo) {
#pragma unroll
    for (int j = 0; j < 8; ++j) {
        const float x = x8[j];
        const __bf16 h = (__bf16)x;
        const float  r = x - (float)h;
        hi[j] = h;
        lo[j] = (__bf16)r;
    }
}

// async global->LDS, 16B/lane, wave-uniform dest base + lane*16
__device__ __forceinline__ void gload_lds16(const void* g, void* l) {
    __builtin_amdgcn_global_load_lds(
        (const __attribute__((address_space(1))) void*)g,
        (__attribute__((address_space(3))) void*)l, 16, 0, 0);
}

// ---- pre-kernel (R8-R17 verified): W fp32 -> B-fragment-ordered bf16 hi/lo.
// Fragment F = S*4 + e (S = k-step of 32): lane l supplies
// B[col 16e+(l&15)][k 32S+8(l>>4)+j] at ws[F*512 + l*8].
__global__ __launch_bounds__(512) void wconv_kernel(
    const float* __restrict__ W, ushort* __restrict__ wsHi, ushort* __restrict__ wsLo)
{
    const int gid = blockIdx.x * blockDim.x + threadIdx.x;   // 0..32767
    const int S = gid >> 8;
    const int e = (gid >> 6) & 3;
    const int l = gid & 63;
    const int row = 16 * e + (l & 15);
    const int k0  = 32 * S + 8 * (l >> 4);
    const float* src = W + (size_t)row * HIDDEN + k0;
    float x8[8];
    *(float4*)&x8[0] = *(const float4*)src;
    *(float4*)&x8[4] = *(const float4*)(src + 4);
    BfU hi, lo;
    cvt_hilo(x8, hi.b, lo.b);
    const size_t o = ((size_t)(S * 4 + e) * 64 + l) * 8;
    *(uint4*)(wsHi + o) = hi.u;
    *(uint4*)(wsLo + o) = lo.u;
}

// ---- gemm half (R17 VERBATIM -- session best, 67.0us): counted-vmcnt
// 2-barrier pipeline, 2 blocks/CU (512 blocks = 256 tiles x 2 K-halves;
// LDS 64KB/block). Co-resident block covers B1 barrier windows (convoy fix:
// R14 1-block=70.6, R17 2-block=67.0, R19 4-block=70.9). 8 waves = tg(4) x
// kh(2); acc[4]; vmcnt(4) + raw s_barrier keeps chunk c+1's loads in
// flight across barriers. Raw 64x64 partial out (no bias).
__global__ __launch_bounds__(512, 2) void gemm_half_kernel(
    const float* __restrict__ X,
    const ushort* __restrict__ wsHi, const ushort* __restrict__ wsLo,
    float* __restrict__ outLog, float* __restrict__ wsP, int nTok)
{
    __shared__ float smem[2 * PAR_FL];   // 65536 B; epilogue aliases

    const int tid = threadIdx.x;
    const int wv  = tid >> 6;        // 0..7
    const int tg  = wv >> 1;         // token-group 0..3
    const int kh  = wv & 1;          // k-step within chunk 0..1
    const int l   = tid & 63;
    const int g   = l >> 4;          // k-slot group 0..3
    const int cr  = l & 15;          // A row / B col within tile
    const int bx  = blockIdx.x;
    const int h   = bx & 1;          // K-half
    const int t0  = (bx >> 1) * TOKS;

    // X staging (R13/R17-verified KCH=64 forms): instr q=2wv+r covers rows
    // 4q..4q+3 (256B each); lane l -> row 4q+(l>>4), granule l&15; source
    // granule (l&8)|((l&7)^(row&7)) (involution).
    const float* XgS[2];
    int xdst[2];
#pragma unroll
    for (int r = 0; r < 2; ++r) {
        const int q    = 2 * wv + r;
        const int srow = 4 * q + (l >> 4);
        const int sgr  = (l & 8) | ((l & 7) ^ (srow & 7));
        XgS[r]  = X + (size_t)(t0 + srow) * HIDDEN + h * KBLK + sgr * 4;
        xdst[r] = 4 * q * KCH;       // floats (uniform base)
    }
    // B staging: chunk window = frags [h*256 + 8c, +8) per plane; wave wv
    // stages hi frag slot wv and lo frag slot wv (1KB linear each).
    const ushort* BhS = wsHi + (size_t)h * 131072 + (size_t)wv * 512 + (size_t)l * 8;
    const ushort* BlS = wsLo + (size_t)h * 131072 + (size_t)wv * 512 + (size_t)l * 8;
    const int bhdst = X_FL + wv * 256;
    const int bldst = X_FL + 2048 + wv * 256;

    // A-frag read: row 16tg+cr; k-step kh; granule 8kh + ((2g+h')^(cr&7)).
    const int m8   = cr & 7;
    const int rowX = (16 * tg + cr) * KCH;
    const int gA0  = (8 * kh + ((2 * g + 0) ^ m8)) << 2;
    const int gA1  = (8 * kh + ((2 * g + 1) ^ m8)) << 2;

    f32x4 acc[4] = {{0.f,0.f,0.f,0.f},{0.f,0.f,0.f,0.f},{0.f,0.f,0.f,0.f},{0.f,0.f,0.f,0.f}};

    // prologue: stage chunk 0 -> parity 0, chunk 1 -> parity 1
#pragma unroll
    for (int r = 0; r < 2; ++r) gload_lds16(XgS[r], smem + xdst[r]);
    gload_lds16(BhS, smem + bhdst);
    gload_lds16(BlS, smem + bldst);
#pragma unroll
    for (int r = 0; r < 2; ++r) gload_lds16(XgS[r] + KCH, smem + PAR_FL + xdst[r]);
    gload_lds16(BhS + 4096, smem + PAR_FL + bhdst);
    gload_lds16(BlS + 4096, smem + PAR_FL + bldst);

#pragma unroll 1
    for (int c = 0; c < NCHK; ++c) {
        if (c + 1 < NCHK) asm volatile("s_waitcnt vmcnt(4)" ::: "memory");
        else              asm volatile("s_waitcnt vmcnt(0)" ::: "memory");
        __builtin_amdgcn_s_barrier();          // B1: chunk c staged & visible
        const int p = c & 1;
        {
            const float*  xb = smem + p * PAR_FL;
            const ushort* bh = (const ushort*)(xb + X_FL) + (4 * kh) * 512 + l * 8;
            const ushort* bl = bh + 4096;      // Blo region (+2048 floats)
            float x8[8];
            *(float4*)&x8[0] = *(const float4*)(xb + rowX + gA0);
            *(float4*)&x8[4] = *(const float4*)(xb + rowX + gA1);
            bf16x8 xh, xo; cvt_hilo(x8, xh, xo);
#pragma unroll
            for (int e = 0; e < 4; ++e) {
                BfU ph, pl;
                ph.u = *(const uint4*)(bh + e * 512);
                pl.u = *(const uint4*)(bl + e * 512);
                acc[e] = __builtin_amdgcn_mfma_f32_16x16x32_bf16(xh, ph.b, acc[e], 0, 0, 0);
                acc[e] = __builtin_amdgcn_mfma_f32_16x16x32_bf16(xo, ph.b, acc[e], 0, 0, 0);
                acc[e] = __builtin_amdgcn_mfma_f32_16x16x32_bf16(xh, pl.b, acc[e], 0, 0, 0);
            }
        }
        __builtin_amdgcn_s_barrier();          // B2: all reads of parity p done
        if (c + 2 < NCHK) {                    // issue c+2 -> parity p (freed)
            float* pb = smem + p * PAR_FL;
            const int ko = (c + 2) * KCH;
            const size_t bo = (size_t)(c + 2) * 4096;
#pragma unroll
            for (int r = 0; r < 2; ++r) gload_lds16(XgS[r] + ko, pb + xdst[r]);
            gload_lds16(BhS + bo, pb + bhdst);
            gload_lds16(BlS + bo, pb + bldst);
        }
    }

    __syncthreads();   // full drain; safe to alias LDS

    // ---- combine kh partials in LDS; write raw 64x64 partial (no bias)
    float (*tiles)[64][68] = (float (*)[64][68])smem;   // 2*64*68 floats
#pragma unroll
    for (int e = 0; e < 4; ++e)
#pragma unroll
        for (int i = 0; i < 4; ++i)
            tiles[kh][16 * tg + 4 * g + i][16 * e + cr] = acc[e][i];   // C/D (m89)
    __syncthreads();

    {
        float* dst = (h ? wsP : outLog) + (size_t)t0 * NEXP;
        const int tok = tid >> 3;          // 0..63
        const int e8  = (tid & 7) * 8;
        float v[8];
#pragma unroll
        for (int j = 0; j < 8; ++j)
            v[j] = tiles[0][tok][e8 + j] + tiles[1][tok][e8 + j];
        float* rowp = dst + (size_t)tok * NEXP + e8;
        *(float4*)rowp       = make_float4(v[0], v[1], v[2], v[3]);
        *(float4*)(rowp + 4) = make_float4(v[4], v[5], v[6], v[7]);
    }
}

// Combine (R7/R17-verified): logits = partial0 (logits region) + partial1
// (ws) + bias; top-2 + softmax, strict > keeps lowest index (jax top_k).
__global__ __launch_bounds__(256) void combine_kernel(
    const float* __restrict__ wsP,
    const float* __restrict__ Bv,
    float* __restrict__ out, int nTok)
{
    __shared__ float tt[64 * 65];
    const int tid = threadIdx.x;
    const int t0  = blockIdx.x * TOKS;
    const size_t offSel = (size_t)nTok * 2;
    const size_t offLog = (size_t)nTok * 4;
    float*       L = out + offLog + (size_t)t0 * NEXP;
    const float* P = wsP + (size_t)t0 * NEXP;

#pragma unroll
    for (int r = 0; r < 4; ++r) {
        const int idx = r * 256 + tid;        // 0..1023 float4-chunks
        const int tok = idx >> 4;
        const int e4  = (idx & 15) * 4;
        const float4 a  = *(const float4*)(L + tok * NEXP + e4);
        const float4 b  = *(const float4*)(P + tok * NEXP + e4);
        const float4 bb = *(const float4*)(Bv + e4);
        const float4 s = make_float4(a.x + b.x + bb.x, a.y + b.y + bb.y,
                                     a.z + b.z + bb.z, a.w + b.w + bb.w);
        *(float4*)(L + tok * NEXP + e4) = s;
        tt[(e4 + 0) * 65 + tok] = s.x;
        tt[(e4 + 1) * 65 + tok] = s.y;
        tt[(e4 + 2) * 65 + tok] = s.z;
        tt[(e4 + 3) * 65 + tok] = s.w;
    }
    __syncthreads();

    if (tid < 64) {
        const int t = tid;
        float m1 = -INFINITY, m2 = -INFINITY;
        int i1 = 0, i2 = 0;
#pragma unroll
        for (int e = 0; e < NEXP; ++e) {
            const float v = tt[e * 65 + t];
            if (v > m1)      { m2 = m1; i2 = i1; m1 = v; i1 = e; }
            else if (v > m2) { m2 = v; i2 = e; }
        }
        const float ex  = expf(m2 - m1);
        const float inv = 1.0f / (1.0f + ex);
        *(float2*)(out + (size_t)(t0 + tid) * 2)          = make_float2(inv, ex * inv);
        *(float2*)(out + offSel + (size_t)(t0 + tid) * 2) = make_float2((float)i1, (float)i2);
    }

    if (blockIdx.x == 0 && tid == 0)
        out[offLog + (size_t)nTok * NEXP] = 0.0f;   // aux_loss
}

extern "C" void kernel_launch(void* const* d_in, const int* in_sizes, int n_in,
                              void* d_out, int out_size, void* d_ws, size_t ws_size,
                              hipStream_t stream)
{
    const float* X  = (const float*)d_in[0];
    const float* W  = (const float*)d_in[1];
    const float* Bv = (const float*)d_in[2];
    float* out = (float*)d_out;
    const int nTok  = in_sizes[0] / HIDDEN;   // 16384
    const int tiles = nTok / TOKS;            // 256
    ushort* wsHi = (ushort*)d_ws;             // 512 KB
    ushort* wsLo = wsHi + (size_t)NEXP * HIDDEN;     // 512 KB
    float*  wsP  = (float*)(wsLo + (size_t)NEXP * HIDDEN);  // 4 MB partials
    float*  outLog = out + (size_t)nTok * 4;

    wconv_kernel<<<256, 128, 0, stream>>>(W, wsHi, wsLo);
    gemm_half_kernel<<<2 * tiles, 512, 0, stream>>>(X, wsHi, wsLo, outLog, wsP, nTok);
    combine_kernel<<<tiles, 256, 0, stream>>>(wsP, Bv, out, nTok);
}